// Round 9
// baseline (640.830 us; speedup 1.0000x reference)
//
#include <hip/hip_runtime.h>
#include <hip/hip_bf16.h>

#define D 256
#define K 8192
#define NTOT 32768
#define BM 128
#define BN2 128
#define BD 32
#define CSPLIT 2
#define CT_PER (K / CSPLIT / BN2)  // 32 code-tiles per block

typedef __bf16 bf16x8 __attribute__((ext_vector_type(8)));
typedef float f32x4 __attribute__((ext_vector_type(4)));

__device__ __forceinline__ void gl_lds16(const void* g, void* l) {
    __builtin_amdgcn_global_load_lds(
        (__attribute__((address_space(1))) void*)(g),
        (__attribute__((address_space(3))) void*)(l), 16, 0, 0);
}

__device__ __forceinline__ unsigned int enc_f32(float f) {
    unsigned int u = __float_as_uint(f);
    return (u & 0x80000000u) ? ~u : (u | 0x80000000u);
}

__device__ __forceinline__ unsigned short f2bfu(float x) {
    __hip_bfloat16 h = __float2bfloat16(x);
    return __builtin_bit_cast(unsigned short, h);
}
__device__ __forceinline__ float bfu2f(unsigned short u) {
    return __bfloat162float(__builtin_bit_cast(__hip_bfloat16, u));
}

// ---------- z -> Fhi/Flo bf16 [NTOT, D] ----------
__global__ __launch_bounds__(256)
void conv_F(const float* __restrict__ z, unsigned short* __restrict__ Fhi,
            unsigned short* __restrict__ Flo) {
    int i4 = blockIdx.x * 256 + threadIdx.x;
    float4 v = ((const float4*)z)[i4];
    ushort4 h, l;
    h.x = f2bfu(v.x); l.x = f2bfu(v.x - bfu2f(h.x));
    h.y = f2bfu(v.y); l.y = f2bfu(v.y - bfu2f(h.y));
    h.z = f2bfu(v.z); l.z = f2bfu(v.z - bfu2f(h.z));
    h.w = f2bfu(v.w); l.w = f2bfu(v.w - bfu2f(h.w));
    ((ushort4*)Fhi)[i4] = h;
    ((ushort4*)Flo)[i4] = l;
}

// ---------- embed [D,K] -> EhiT/EloT bf16 [K,D] + ET fp32 [K,D]
//            + enorm (fused, atomic-accumulated) + sum(cs_in) ----------
__global__ __launch_bounds__(256)
void conv_E(const float* __restrict__ E, const float* __restrict__ cs_in,
            unsigned short* __restrict__ EhiT, unsigned short* __restrict__ EloT,
            float* __restrict__ ET, float* __restrict__ enorm,
            float* __restrict__ nsum) {
    __shared__ float tile[64][65];
    int tid = threadIdx.x;
    int k0 = blockIdx.x * 64, d0 = blockIdx.y * 64;

    if (blockIdx.y == 0 && tid < 64) {
        float s = cs_in[k0 + tid];
#pragma unroll
        for (int off = 32; off; off >>= 1) s += __shfl_down(s, off);
        if (tid == 0) atomicAdd(nsum, s);
    }

#pragma unroll
    for (int it = 0; it < 16; ++it) {
        int idx = it * 256 + tid;
        int dr = idx >> 6, kc = idx & 63;
        tile[kc][dr] = E[(d0 + dr) * K + k0 + kc];
    }
    __syncthreads();
#pragma unroll
    for (int it = 0; it < 16; ++it) {
        int idx = it * 256 + tid;
        int kr = idx >> 6, dc = idx & 63;
        float v = tile[kr][dc];
        unsigned short h = f2bfu(v);
        int o = (k0 + kr) * D + d0 + dc;
        EhiT[o] = h;
        EloT[o] = f2bfu(v - bfu2f(h));
        ET[o] = v;
        float ss = v * v;
#pragma unroll
        for (int off = 32; off; off >>= 1) ss += __shfl_down(ss, off);
        if ((tid & 63) == 0) atomicAdd(&enorm[k0 + kr], ss);
    }
}

// ---------- MFMA dist + fused argmin: A-RESIDENT-IN-LDS variant ----------
// A (hi+lo, 128 KB) staged ONCE per block; K-loop stages only B (16 KB/step).
// Halves fabric traffic (4 GB -> 2.1 GB) and per-step DMA/VALU.
// A layout: addr(row,d) = row*256 + (window^(row&1))*32 + (chunk^((row>>1)&3))*8
//   -> bank slot = 16*((w&1)^(ln&1)) + 4*(qd^((ln>>1)&3)): 2-way max (free).
// B staging/read identical to the proven R0 pattern. Sync = R0's 2-barrier.
__global__ __launch_bounds__(512)
void mfma_dist_argmin(const unsigned short* __restrict__ Fhi,
                      const unsigned short* __restrict__ Flo,
                      const unsigned short* __restrict__ EhiT,
                      const unsigned short* __restrict__ EloT,
                      const float* __restrict__ enorm,
                      unsigned long long* __restrict__ bestpack) {
    __shared__ unsigned short Ahr[BM * D];   // 64 KB resident A hi
    __shared__ unsigned short Alr[BM * D];   // 64 KB resident A lo
    __shared__ unsigned short Bh[BN2 * BD];  // 8 KB per-step B hi
    __shared__ unsigned short Bl[BN2 * BD];  // 8 KB per-step B lo

    const int tid = threadIdx.x;   // 0..511
    const int wave = tid >> 6;     // 0..7
    const int lane = tid & 63;
    const int qd = lane >> 4;
    const int ln = lane & 15;
    const int wm = (wave >> 2) * 64;  // rows 0 / 64
    const int wn = (wave & 3) * 32;   // cols 0,32,64,96
    const int n0 = blockIdx.x * BM;
    const int c0 = blockIdx.y * (K / CSPLIT);
    // read swizzle (within 32-d window), same as proven R0 pattern
    const int csw = (qd ^ ((ln >> 1) & 3)) * 8;

    // ---- stage resident A (16 issues of 8 KB) ----
#pragma unroll
    for (int i = 0; i < 8; ++i) {
        const int row = i * 16 + (tid >> 5);       // 0..127
        const int pw = (tid & 31) >> 2;            // physical window 0..7
        const int pc = tid & 3;                    // physical chunk 0..3
        const int gw = pw ^ (row & 1);
        const int gc = pc ^ ((row >> 1) & 3);
        const int ga = (n0 + row) * D + gw * 32 + gc * 8;
        gl_lds16(Fhi + ga, &Ahr[i * 4096 + wave * 512]);
        gl_lds16(Flo + ga, &Alr[i * 4096 + wave * 512]);
    }

    // B staging map (per step): thread t -> (row=t>>2, chunk=t&3), src pre-swizzled
    const int brow = tid >> 2;
    const int bsw = (tid & 3) ^ ((tid >> 3) & 3);

    float bestv[16];
    int besti[16];
#pragma unroll
    for (int i = 0; i < 16; ++i) { bestv[i] = 3.402823466e38f; besti[i] = 0; }

    for (int ct = 0; ct < CT_PER; ++ct) {
        const int cb = c0 + ct * BN2;
        f32x4 acc[4][2];
#pragma unroll
        for (int mi = 0; mi < 4; ++mi)
#pragma unroll
            for (int ni = 0; ni < 2; ++ni) acc[mi][ni] = (f32x4){0.f, 0.f, 0.f, 0.f};

        for (int d0 = 0; d0 < D; d0 += BD) {
            __syncthreads();  // prev step's readers done (also drains A DMA on step 0)
            {
                const int gb = (cb + brow) * D + d0 + bsw * 8;
                gl_lds16(EhiT + gb, &Bh[wave * 512]);
                gl_lds16(EloT + gb, &Bl[wave * 512]);
            }
            __syncthreads();  // staging complete

            const int w = d0 >> 5;  // window index
            bf16x8 ah[4], al[4], bh[2], bl[2];
#pragma unroll
            for (int mi = 0; mi < 4; ++mi) {
                const int arow = wm + mi * 16 + ln;
                const int aoff = arow * D + ((w ^ (arow & 1)) << 5) + csw;
                ah[mi] = *(const bf16x8*)&Ahr[aoff];
                al[mi] = *(const bf16x8*)&Alr[aoff];
            }
#pragma unroll
            for (int ni = 0; ni < 2; ++ni) {
                const int boff = (wn + ni * 16 + ln) * BD + csw;
                bh[ni] = *(const bf16x8*)&Bh[boff];
                bl[ni] = *(const bf16x8*)&Bl[boff];
            }

#pragma unroll
            for (int mi = 0; mi < 4; ++mi)
#pragma unroll
                for (int ni = 0; ni < 2; ++ni)
                    acc[mi][ni] = __builtin_amdgcn_mfma_f32_16x16x32_bf16(
                        ah[mi], bh[ni], acc[mi][ni], 0, 0, 0);
#pragma unroll
            for (int mi = 0; mi < 4; ++mi)
#pragma unroll
                for (int ni = 0; ni < 2; ++ni)
                    acc[mi][ni] = __builtin_amdgcn_mfma_f32_16x16x32_bf16(
                        ah[mi], bl[ni], acc[mi][ni], 0, 0, 0);
#pragma unroll
            for (int mi = 0; mi < 4; ++mi)
#pragma unroll
                for (int ni = 0; ni < 2; ++ni)
                    acc[mi][ni] = __builtin_amdgcn_mfma_f32_16x16x32_bf16(
                        al[mi], bh[ni], acc[mi][ni], 0, 0, 0);
        }

        float en[2];
#pragma unroll
        for (int ni = 0; ni < 2; ++ni) en[ni] = enorm[cb + wn + ni * 16 + ln];
#pragma unroll
        for (int ni = 0; ni < 2; ++ni) {
            const int k = cb + wn + ni * 16 + ln;
#pragma unroll
            for (int mi = 0; mi < 4; ++mi) {
                f32x4 a = acc[mi][ni];
#pragma unroll
                for (int r = 0; r < 4; ++r) {
                    float dist = en[ni] - 2.0f * a[r];
                    int bi = mi * 4 + r;
                    if (dist < bestv[bi]) { bestv[bi] = dist; besti[bi] = k; }
                }
            }
        }
    }

#pragma unroll
    for (int mi = 0; mi < 4; ++mi) {
#pragma unroll
        for (int r = 0; r < 4; ++r) {
            int bi = mi * 4 + r;
            float v = bestv[bi];
            int ix = besti[bi];
#pragma unroll
            for (int off = 1; off < 16; off <<= 1) {
                float v2 = __shfl_xor(v, off);
                int i2 = __shfl_xor(ix, off);
                if (v2 < v || (v2 == v && i2 < ix)) { v = v2; ix = i2; }
            }
            if (ln == 0) {
                int m = n0 + wm + mi * 16 + qd * 4 + r;
                unsigned long long pack =
                    ((unsigned long long)enc_f32(v) << 32) | (unsigned int)ix;
                atomicMin(&bestpack[m], pack);
            }
        }
    }
}

// ---------- gather quantize, diff partial, segment-sum scatter ----------
#define ROWS_PER_BLOCK 16
__global__ __launch_bounds__(256)
void assign_apply(const float* __restrict__ z,   // [NTOT, D]
                  const float* __restrict__ ET,  // [K, D]
                  const unsigned long long* __restrict__ bestpack,
                  float* __restrict__ out_q, float* __restrict__ out_ind,
                  float* __restrict__ counts, float* __restrict__ esumT,
                  float* __restrict__ diffpart) {
    const int tx = threadIdx.x;  // = d
    const int rbase = blockIdx.x * ROWS_PER_BLOCK;
    float part = 0.f;
    for (int r = 0; r < ROWS_PER_BLOCK; ++r) {
        int n = rbase + r;
        unsigned long long p = bestpack[n];
        int idx = (int)(p & 0xFFFFFFFFull);
        float f = z[n * D + tx];
        float q = ET[idx * D + tx];
        out_q[n * D + tx] = q;
        float dd = q - f;
        part += dd * dd;
        atomicAdd(&esumT[idx * D + tx], f);
        if (tx == 0) {
            atomicAdd(&counts[idx], 1.0f);
            out_ind[n] = (float)idx;
        }
    }
#pragma unroll
    for (int off = 32; off; off >>= 1) part += __shfl_down(part, off);
    __shared__ float wsum[4];
    if ((tx & 63) == 0) wsum[tx >> 6] = part;
    __syncthreads();
    if (tx == 0) diffpart[blockIdx.x] = wsum[0] + wsum[1] + wsum[2] + wsum[3];
}

// ---------- embed_new (csn/nsum fused) + diff final reduce ----------
__global__ __launch_bounds__(256)
void finalize(const float* __restrict__ eavg, const float* __restrict__ esumT,
              const float* __restrict__ cs_in, const float* __restrict__ counts,
              const float* __restrict__ nsum, const float* __restrict__ diffpart,
              float* __restrict__ out_enew, float* __restrict__ out_diff) {
    const int tid = threadIdx.x;
    if (blockIdx.x == 0) {
        float p = 0.f;
#pragma unroll
        for (int j = 0; j < 8; ++j) p += diffpart[tid + 256 * j];  // 2048 partials
#pragma unroll
        for (int off = 32; off; off >>= 1) p += __shfl_down(p, off);
        __shared__ float sred[4];
        if ((tid & 63) == 0) sred[tid >> 6] = p;
        __syncthreads();
        if (tid == 0)
            *out_diff = (sred[0] + sred[1] + sred[2] + sred[3]) * (0.25f / 8388608.0f);
    }
    const int idx = blockIdx.x * 256 + tid;  // d*K + k
    const float nv = 0.99f * nsum[0] + 0.01f * 32768.0f;  // sum(counts) == NTOT exact
    const int k = idx & (K - 1);
    const int d = idx >> 13;
    const float csn_k = 0.99f * cs_in[k] + 0.01f * counts[k];
    const float avg_new = 0.99f * eavg[idx] + 0.01f * esumT[k * D + d];
    const float cs = (csn_k + 1e-5f) / (nv + 0.08192f) * nv;
    out_enew[idx] = avg_new / cs;
}

extern "C" void kernel_launch(void* const* d_in, const int* in_sizes, int n_in,
                              void* d_out, int out_size, void* d_ws, size_t ws_size,
                              hipStream_t stream) {
    const float* z = (const float*)d_in[0];      // [32,32,32,256]
    const float* embed = (const float*)d_in[1];  // [256, 8192]
    const float* cs_in = (const float*)d_in[2];  // [8192]
    const float* eavg = (const float*)d_in[3];   // [256, 8192]

    float* out = (float*)d_out;
    float* out_q = out;                  // 8388608
    float* out_diff = out + 8388608;     // 1
    float* out_ind = out + 8388609;      // 32768
    float* out_enew = out + 8421377;     // 2097152

    char* ws = (char*)d_ws;
    unsigned long long* bestpack = (unsigned long long*)ws;   // 256 KB (0xFF)
    float* counts = (float*)(ws + 262144);                    // 32 KB (zero)
    float* nsum = (float*)(ws + 294912);                      // 256 B (zero)
    float* enorm = (float*)(ws + 295168);                     // 32 KB (zero, accumulated)
    float* esumT = (float*)(ws + 327936);                     // 8 MB  (zero) [K,D]
    unsigned short* Fhi = (unsigned short*)(ws + 8716544);    // 16 MB
    unsigned short* Flo = (unsigned short*)(ws + 25493760);   // 16 MB
    unsigned short* EhiT = (unsigned short*)(ws + 42270976);  // 4 MB
    unsigned short* EloT = (unsigned short*)(ws + 46465280);  // 4 MB
    float* ET = (float*)(ws + 50659584);                      // 8 MB -> end 59048192
    // diffpart aliases the head of Fhi (dead after mfma_dist_argmin)
    float* diffpart = (float*)(ws + 8716544);                 // 8 KB

    hipMemsetAsync(bestpack, 0xFF, 262144, stream);
    hipMemsetAsync(ws + 262144, 0, 8454400, stream);  // counts+nsum+enorm+esumT

    conv_F<<<NTOT * D / 4 / 256, 256, 0, stream>>>(z, Fhi, Flo);
    conv_E<<<dim3(K / 64, D / 64), 256, 0, stream>>>(embed, cs_in, EhiT, EloT, ET,
                                                     enorm, nsum);
    mfma_dist_argmin<<<dim3(NTOT / BM, CSPLIT), 512, 0, stream>>>(Fhi, Flo, EhiT, EloT,
                                                                  enorm, bestpack);
    assign_apply<<<NTOT / ROWS_PER_BLOCK, 256, 0, stream>>>(z, ET, bestpack, out_q,
                                                            out_ind, counts, esumT,
                                                            diffpart);
    finalize<<<(D * K) / 256, 256, 0, stream>>>(eavg, esumT, cs_in, counts, nsum,
                                                diffpart, out_enew, out_diff);
}

// Round 10
// 591.250 us; speedup vs baseline: 1.0839x; 1.0839x over previous
//
#include <hip/hip_runtime.h>
#include <hip/hip_bf16.h>

#define D 256
#define K 8192
#define NTOT 32768
#define BM 128
#define BN2 128
#define BD 32
#define CSPLIT 4
#define CT_PER (K / CSPLIT / BN2)  // 16 code-tiles per block

typedef __bf16 bf16x8 __attribute__((ext_vector_type(8)));
typedef float f32x4 __attribute__((ext_vector_type(4)));

__device__ __forceinline__ void gl_lds16(const void* g, void* l) {
    __builtin_amdgcn_global_load_lds(
        (__attribute__((address_space(1))) void*)(g),
        (__attribute__((address_space(3))) void*)(l), 16, 0, 0);
}

__device__ __forceinline__ unsigned int enc_f32(float f) {
    unsigned int u = __float_as_uint(f);
    return (u & 0x80000000u) ? ~u : (u | 0x80000000u);
}

__device__ __forceinline__ unsigned short f2bfu(float x) {
    __hip_bfloat16 h = __float2bfloat16(x);
    return __builtin_bit_cast(unsigned short, h);
}
__device__ __forceinline__ float bfu2f(unsigned short u) {
    return __bfloat162float(__builtin_bit_cast(__hip_bfloat16, u));
}

// ---------- z -> Fhi/Flo bf16 [NTOT, D] ----------
__global__ __launch_bounds__(256)
void conv_F(const float* __restrict__ z, unsigned short* __restrict__ Fhi,
            unsigned short* __restrict__ Flo) {
    int i4 = blockIdx.x * 256 + threadIdx.x;
    float4 v = ((const float4*)z)[i4];
    ushort4 h, l;
    h.x = f2bfu(v.x); l.x = f2bfu(v.x - bfu2f(h.x));
    h.y = f2bfu(v.y); l.y = f2bfu(v.y - bfu2f(h.y));
    h.z = f2bfu(v.z); l.z = f2bfu(v.z - bfu2f(h.z));
    h.w = f2bfu(v.w); l.w = f2bfu(v.w - bfu2f(h.w));
    ((ushort4*)Fhi)[i4] = h;
    ((ushort4*)Flo)[i4] = l;
}

// ---------- embed [D,K] -> EhiT/EloT bf16 [K,D] + ET fp32 [K,D]
//            + enorm (fused, atomic-accumulated) + sum(cs_in) ----------
__global__ __launch_bounds__(256)
void conv_E(const float* __restrict__ E, const float* __restrict__ cs_in,
            unsigned short* __restrict__ EhiT, unsigned short* __restrict__ EloT,
            float* __restrict__ ET, float* __restrict__ enorm,
            float* __restrict__ nsum) {
    __shared__ float tile[64][65];
    int tid = threadIdx.x;
    int k0 = blockIdx.x * 64, d0 = blockIdx.y * 64;

    if (blockIdx.y == 0 && tid < 64) {
        float s = cs_in[k0 + tid];
#pragma unroll
        for (int off = 32; off; off >>= 1) s += __shfl_down(s, off);
        if (tid == 0) atomicAdd(nsum, s);
    }

#pragma unroll
    for (int it = 0; it < 16; ++it) {
        int idx = it * 256 + tid;
        int dr = idx >> 6, kc = idx & 63;
        tile[kc][dr] = E[(d0 + dr) * K + k0 + kc];
    }
    __syncthreads();
#pragma unroll
    for (int it = 0; it < 16; ++it) {
        int idx = it * 256 + tid;
        int kr = idx >> 6, dc = idx & 63;
        float v = tile[kr][dc];
        unsigned short h = f2bfu(v);
        int o = (k0 + kr) * D + d0 + dc;
        EhiT[o] = h;
        EloT[o] = f2bfu(v - bfu2f(h));
        ET[o] = v;
        float ss = v * v;
#pragma unroll
        for (int off = 32; off; off >>= 1) ss += __shfl_down(ss, off);
        if ((tid & 63) == 0) atomicAdd(&enorm[k0 + kr], ss);
    }
}

// ---------- MFMA dist + fused argmin (R8 structure + strength-reduced staging) ----------
// Identical LDS/barrier/read/MFMA/fold structure to the proven 437 us kernel;
// the only change: staging addresses advance incrementally (+BD/step, A rewinds
// -D per ct, B jumps +BN2*D-D per ct) instead of full recomputation -> removes
// the per-step v_lshl_add_u64 chains (asm: ~21/step) from the VALU pipe.
__global__ __launch_bounds__(256)
void mfma_dist_argmin(const unsigned short* __restrict__ Fhi,
                      const unsigned short* __restrict__ Flo,
                      const unsigned short* __restrict__ EhiT,
                      const unsigned short* __restrict__ EloT,
                      const float* __restrict__ enorm,
                      unsigned long long* __restrict__ bestpack) {
    __shared__ unsigned short Ah[BM * BD], Al[BM * BD], Bh[BN2 * BD], Bl[BN2 * BD];

    const int tid = threadIdx.x;
    const int wave = tid >> 6;
    const int lane = tid & 63;
    const int qd = lane >> 4;
    const int ln = lane & 15;
    const int wm = (wave >> 1) * 64;
    const int wn = (wave & 1) * 64;
    const int n0 = blockIdx.x * BM;
    const int c0 = blockIdx.y * (K / CSPLIT);
    // staging: lane tid -> physical (row tid>>2, chunk tid&3); swizzled global chunk
    const int r_ = tid >> 2;
    const int s_sw = (tid & 3) ^ ((tid >> 3) & 3);
    // read swizzle: logical chunk qd of row ln lives at physical chunk qd^((ln>>1)&3)
    const int csw = (qd ^ ((ln >> 1) & 3)) * 8;

    // incremental staging offsets (32-bit element offsets)
    int gA0 = (n0 + r_) * D + s_sw * 8;
    int gA1 = gA0 + 64 * D;
    int gB0 = (c0 + r_) * D + s_sw * 8;
    int gB1 = gB0 + 64 * D;
    const int loL = wave * 512;         // it=0 LDS short-offset
    const int loH = 2048 + wave * 512;  // it=1

    float bestv[16];
    int besti[16];
#pragma unroll
    for (int i = 0; i < 16; ++i) { bestv[i] = 3.402823466e38f; besti[i] = 0; }

    for (int ct = 0; ct < CT_PER; ++ct) {
        const int cb = c0 + ct * BN2;
        f32x4 acc[4][4];
#pragma unroll
        for (int mi = 0; mi < 4; ++mi)
#pragma unroll
            for (int ni = 0; ni < 4; ++ni) acc[mi][ni] = (f32x4){0.f, 0.f, 0.f, 0.f};

        for (int d0 = 0; d0 < D; d0 += BD) {
            __syncthreads();
            gl_lds16(Fhi + gA0, &Ah[loL]);
            gl_lds16(Flo + gA0, &Al[loL]);
            gl_lds16(Fhi + gA1, &Ah[loH]);
            gl_lds16(Flo + gA1, &Al[loH]);
            gl_lds16(EhiT + gB0, &Bh[loL]);
            gl_lds16(EloT + gB0, &Bl[loL]);
            gl_lds16(EhiT + gB1, &Bh[loH]);
            gl_lds16(EloT + gB1, &Bl[loH]);
            gA0 += BD; gA1 += BD; gB0 += BD; gB1 += BD;
            __syncthreads();

            bf16x8 ah[4], al[4], bh[4], bl[4];
#pragma unroll
            for (int mi = 0; mi < 4; ++mi) {
                int off = (wm + mi * 16 + ln) * BD + csw;
                ah[mi] = *(const bf16x8*)&Ah[off];
                al[mi] = *(const bf16x8*)&Al[off];
            }
#pragma unroll
            for (int ni = 0; ni < 4; ++ni) {
                int off = (wn + ni * 16 + ln) * BD + csw;
                bh[ni] = *(const bf16x8*)&Bh[off];
                bl[ni] = *(const bf16x8*)&Bl[off];
            }
#pragma unroll
            for (int mi = 0; mi < 4; ++mi)
#pragma unroll
                for (int ni = 0; ni < 4; ++ni)
                    acc[mi][ni] = __builtin_amdgcn_mfma_f32_16x16x32_bf16(
                        ah[mi], bh[ni], acc[mi][ni], 0, 0, 0);
#pragma unroll
            for (int mi = 0; mi < 4; ++mi)
#pragma unroll
                for (int ni = 0; ni < 4; ++ni)
                    acc[mi][ni] = __builtin_amdgcn_mfma_f32_16x16x32_bf16(
                        ah[mi], bl[ni], acc[mi][ni], 0, 0, 0);
#pragma unroll
            for (int mi = 0; mi < 4; ++mi)
#pragma unroll
                for (int ni = 0; ni < 4; ++ni)
                    acc[mi][ni] = __builtin_amdgcn_mfma_f32_16x16x32_bf16(
                        al[mi], bh[ni], acc[mi][ni], 0, 0, 0);
        }
        // A panel repeats every code tile; B advances to the next 128 rows
        gA0 -= D; gA1 -= D;
        gB0 += BN2 * D - D; gB1 += BN2 * D - D;

        float en[4];
#pragma unroll
        for (int ni = 0; ni < 4; ++ni) en[ni] = enorm[cb + wn + ni * 16 + ln];
#pragma unroll
        for (int ni = 0; ni < 4; ++ni) {
            int k = cb + wn + ni * 16 + ln;
#pragma unroll
            for (int mi = 0; mi < 4; ++mi) {
                f32x4 a = acc[mi][ni];
#pragma unroll
                for (int r = 0; r < 4; ++r) {
                    float dist = en[ni] - 2.0f * a[r];
                    int bi = mi * 4 + r;
                    if (dist < bestv[bi]) { bestv[bi] = dist; besti[bi] = k; }
                }
            }
        }
    }

#pragma unroll
    for (int mi = 0; mi < 4; ++mi) {
#pragma unroll
        for (int r = 0; r < 4; ++r) {
            int bi = mi * 4 + r;
            float v = bestv[bi];
            int ix = besti[bi];
#pragma unroll
            for (int off = 1; off < 16; off <<= 1) {
                float v2 = __shfl_xor(v, off);
                int i2 = __shfl_xor(ix, off);
                if (v2 < v || (v2 == v && i2 < ix)) { v = v2; ix = i2; }
            }
            if (ln == 0) {
                int m = n0 + wm + mi * 16 + qd * 4 + r;
                unsigned long long pack =
                    ((unsigned long long)enc_f32(v) << 32) | (unsigned int)ix;
                atomicMin(&bestpack[m], pack);
            }
        }
    }
}

// ---------- gather quantize, diff partial, segment-sum scatter ----------
#define ROWS_PER_BLOCK 16
__global__ __launch_bounds__(256)
void assign_apply(const float* __restrict__ z,   // [NTOT, D]
                  const float* __restrict__ ET,  // [K, D]
                  const unsigned long long* __restrict__ bestpack,
                  float* __restrict__ out_q, float* __restrict__ out_ind,
                  float* __restrict__ counts, float* __restrict__ esumT,
                  float* __restrict__ diffpart) {
    const int tx = threadIdx.x;  // = d
    const int rbase = blockIdx.x * ROWS_PER_BLOCK;
    float part = 0.f;
    for (int r = 0; r < ROWS_PER_BLOCK; ++r) {
        int n = rbase + r;
        unsigned long long p = bestpack[n];
        int idx = (int)(p & 0xFFFFFFFFull);
        float f = z[n * D + tx];
        float q = ET[idx * D + tx];
        out_q[n * D + tx] = q;
        float dd = q - f;
        part += dd * dd;
        atomicAdd(&esumT[idx * D + tx], f);
        if (tx == 0) {
            atomicAdd(&counts[idx], 1.0f);
            out_ind[n] = (float)idx;
        }
    }
#pragma unroll
    for (int off = 32; off; off >>= 1) part += __shfl_down(part, off);
    __shared__ float wsum[4];
    if ((tx & 63) == 0) wsum[tx >> 6] = part;
    __syncthreads();
    if (tx == 0) diffpart[blockIdx.x] = wsum[0] + wsum[1] + wsum[2] + wsum[3];
}

// ---------- embed_new (csn/nsum fused) + diff final reduce ----------
__global__ __launch_bounds__(256)
void finalize(const float* __restrict__ eavg, const float* __restrict__ esumT,
              const float* __restrict__ cs_in, const float* __restrict__ counts,
              const float* __restrict__ nsum, const float* __restrict__ diffpart,
              float* __restrict__ out_enew, float* __restrict__ out_diff) {
    const int tid = threadIdx.x;
    if (blockIdx.x == 0) {
        float p = 0.f;
#pragma unroll
        for (int j = 0; j < 8; ++j) p += diffpart[tid + 256 * j];  // 2048 partials
#pragma unroll
        for (int off = 32; off; off >>= 1) p += __shfl_down(p, off);
        __shared__ float sred[4];
        if ((tid & 63) == 0) sred[tid >> 6] = p;
        __syncthreads();
        if (tid == 0)
            *out_diff = (sred[0] + sred[1] + sred[2] + sred[3]) * (0.25f / 8388608.0f);
    }
    const int idx = blockIdx.x * 256 + tid;  // d*K + k
    const float nv = 0.99f * nsum[0] + 0.01f * 32768.0f;  // sum(counts) == NTOT exact
    const int k = idx & (K - 1);
    const int d = idx >> 13;
    const float csn_k = 0.99f * cs_in[k] + 0.01f * counts[k];
    const float avg_new = 0.99f * eavg[idx] + 0.01f * esumT[k * D + d];
    const float cs = (csn_k + 1e-5f) / (nv + 0.08192f) * nv;
    out_enew[idx] = avg_new / cs;
}

extern "C" void kernel_launch(void* const* d_in, const int* in_sizes, int n_in,
                              void* d_out, int out_size, void* d_ws, size_t ws_size,
                              hipStream_t stream) {
    const float* z = (const float*)d_in[0];      // [32,32,32,256]
    const float* embed = (const float*)d_in[1];  // [256, 8192]
    const float* cs_in = (const float*)d_in[2];  // [8192]
    const float* eavg = (const float*)d_in[3];   // [256, 8192]

    float* out = (float*)d_out;
    float* out_q = out;                  // 8388608
    float* out_diff = out + 8388608;     // 1
    float* out_ind = out + 8388609;      // 32768
    float* out_enew = out + 8421377;     // 2097152

    char* ws = (char*)d_ws;
    unsigned long long* bestpack = (unsigned long long*)ws;   // 256 KB (0xFF)
    float* counts = (float*)(ws + 262144);                    // 32 KB (zero)
    float* nsum = (float*)(ws + 294912);                      // 256 B (zero)
    float* enorm = (float*)(ws + 295168);                     // 32 KB (zero, accumulated)
    float* esumT = (float*)(ws + 327936);                     // 8 MB  (zero) [K,D]
    unsigned short* Fhi = (unsigned short*)(ws + 8716544);    // 16 MB
    unsigned short* Flo = (unsigned short*)(ws + 25493760);   // 16 MB
    unsigned short* EhiT = (unsigned short*)(ws + 42270976);  // 4 MB
    unsigned short* EloT = (unsigned short*)(ws + 46465280);  // 4 MB
    float* ET = (float*)(ws + 50659584);                      // 8 MB -> end 59048192
    // diffpart aliases the head of Fhi (dead after mfma_dist_argmin)
    float* diffpart = (float*)(ws + 8716544);                 // 8 KB

    hipMemsetAsync(bestpack, 0xFF, 262144, stream);
    hipMemsetAsync(ws + 262144, 0, 8454400, stream);  // counts+nsum+enorm+esumT

    conv_F<<<NTOT * D / 4 / 256, 256, 0, stream>>>(z, Fhi, Flo);
    conv_E<<<dim3(K / 64, D / 64), 256, 0, stream>>>(embed, cs_in, EhiT, EloT, ET,
                                                     enorm, nsum);
    mfma_dist_argmin<<<dim3(NTOT / BM, CSPLIT), 256, 0, stream>>>(Fhi, Flo, EhiT, EloT,
                                                                  enorm, bestpack);
    assign_apply<<<NTOT / ROWS_PER_BLOCK, 256, 0, stream>>>(z, ET, bestpack, out_q,
                                                            out_ind, counts, esumT,
                                                            diffpart);
    finalize<<<(D * K) / 256, 256, 0, stream>>>(eavg, esumT, cs_in, counts, nsum,
                                                diffpart, out_enew, out_diff);
}